// Round 14
// baseline (267.144 us; speedup 1.0000x reference)
//
#include <hip/hip_runtime.h>
#include <math.h>

typedef __attribute__((ext_vector_type(8))) short short8;   // 8 x bf16 bits
typedef __attribute__((ext_vector_type(8))) __bf16 bf16x8;  // MFMA operand type
typedef __attribute__((ext_vector_type(4))) float f32x4;
typedef unsigned short ushort_t;

#define DEV __device__ __forceinline__

// ---------------- problem constants ----------------
constexpr int Dm   = 512;
constexpr int DI   = 1024;
constexpr int DR   = 32;
constexpr int Hh   = 16;
constexpr int Wd   = 11;
constexpr int Bm   = 10;          // b * (Sf/T) = 2*5
constexpr int Lq   = 528;         // T*H*W
constexpr int NTOK = Bm * Lq;     // 5280
constexpr int MBAT = 4 * Bm;      // 40 (4 scan paths)
constexpr int MTOK = MBAT * Lq;   // 21120
constexpr int XD_LD = 64;         // padded ld for x_dbl (34 cols used; 34..63 zero)
constexpr int NCHK = 16;          // scan chunks per sequence
constexpr int CHK  = Lq / NCHK;   // 33
constexpr int MPAD = 5376;        // NTOK padded to multiple of 128

// ---------------- bf16 helpers (explicit RNE) ----------------
DEV ushort_t f2bf(float f) {
    unsigned u = __float_as_uint(f);
    u += 0x7fffu + ((u >> 16) & 1u);
    return (ushort_t)(u >> 16);
}
DEV float bf2f(ushort_t h) { return __uint_as_float(((unsigned)h) << 16); }

DEV bf16x8 as_bf(short8 v) { return __builtin_bit_cast(bf16x8, v); }

DEV void mfma_bf16(f32x4& d, short8 a, short8 b) {
    d = __builtin_amdgcn_mfma_f32_16x16x32_bf16(as_bf(a), as_bf(b), d, 0, 0, 0);
}

// async global->LDS, 16B per lane (dest = wave-uniform base + lane*16)
DEV void gll16(const ushort_t* g, ushort_t* l) {
    __builtin_amdgcn_global_load_lds((const __attribute__((address_space(1))) void*)g,
                                     (__attribute__((address_space(3))) void*)l,
                                     16, 0, 0);
}

// counted vmcnt wait (literal immediates; memory clobber pins mem-op order)
template<int N> DEV void vm_wait() {
    if constexpr (N == 0) asm volatile("s_waitcnt vmcnt(0)" ::: "memory");
    else if constexpr (N == 2) asm volatile("s_waitcnt vmcnt(2)" ::: "memory");
    else if constexpr (N == 3) asm volatile("s_waitcnt vmcnt(3)" ::: "memory");
    else if constexpr (N == 4) asm volatile("s_waitcnt vmcnt(4)" ::: "memory");
    else asm volatile("s_waitcnt vmcnt(6)" ::: "memory");
}

// fast erf, Abramowitz-Stegun 7.1.26, |eps| <= 1.5e-7
DEV float fast_erf(float x) {
    const float ax = fabsf(x);
    const float t  = 1.0f / (1.0f + 0.3275911f * ax);
    const float y  = t * (0.254829592f + t * (-0.284496736f + t * (1.421413741f
                   + t * (-1.453152027f + t * 1.061405429f))));
    const float r  = 1.0f - y * __expf(-ax * ax);
    return copysignf(r, x);
}

// path-local index q (in path p's scan order) -> global token index (bi*Lq + l1)
DEV int path_tok(int p, int bi, int q) {
    int ql = (p & 1) ? (Lq - 1 - q) : q;   // paths 1,3 are flipped
    int l1;
    if (p < 2) {
        l1 = ql;
    } else {                               // path 2/3: q encodes (t*Wd+ww)*Hh+hh
        int t   = ql / (Hh * Wd);
        int rem = ql - t * (Hh * Wd);
        int ww  = rem / Hh;
        int hh  = rem - ww * Hh;
        l1 = (t * Hh + hh) * Wd + ww;
    }
    return bi * Lq + l1;
}

// ---------------- small utility kernels ----------------
__global__ void k_f2bf(const float* __restrict__ s, ushort_t* __restrict__ d, int n) {
    int i = blockIdx.x * 256 + threadIdx.x;
    if (i < n) d[i] = f2bf(s[i]);
}
__global__ void k_zero(ushort_t* __restrict__ d, int n) {
    int i = blockIdx.x * 256 + threadIdx.x;
    if (i < n) d[i] = 0;
}
// transpose conv weights [DI][4] -> [4][DI] f32 (coalesced tap access in k_conv)
__global__ void k_cwT(const float* __restrict__ cw, float* __restrict__ cwT) {
    int i = blockIdx.x * 256 + threadIdx.x;   // 4*DI
    if (i < 4 * DI) {
        int d = i / DI, ch = i - d * DI;
        cwT[i] = cw[ch * 4 + d];
    }
}
// dtproj (DI x 32) -> bf16 [DI][64] (cols 32..63 already zeroed)
__global__ void k_cvt_dt(const float* __restrict__ s, ushort_t* __restrict__ d) {
    int i = blockIdx.x * 256 + threadIdx.x;   // DI*32
    if (i < DI * DR) {
        int r = i / DR, c = i - r * DR;
        d[r * 64 + c] = f2bf(s[i]);
    }
}

// ---------------- LN1 (single row per token) ----------------
__global__ void k_ln1(const float* __restrict__ x, const float* __restrict__ g,
                      const float* __restrict__ b, ushort_t* __restrict__ xn) {
    const int tok  = blockIdx.x;     // 0..NTOK-1
    const int lane = threadIdx.x;    // 64 threads
    const int c0   = lane * 8;
    const float* row = x + (size_t)tok * Dm;
    float4 v0 = *(const float4*)(row + c0);
    float4 v1 = *(const float4*)(row + c0 + 4);
    float s  = v0.x + v0.y + v0.z + v0.w + v1.x + v1.y + v1.z + v1.w;
    float ss = v0.x*v0.x + v0.y*v0.y + v0.z*v0.z + v0.w*v0.w
             + v1.x*v1.x + v1.y*v1.y + v1.z*v1.z + v1.w*v1.w;
#pragma unroll
    for (int o = 32; o >= 1; o >>= 1) { s += __shfl_xor(s, o); ss += __shfl_xor(ss, o); }
    const float mean = s * (1.0f / Dm);
    const float rstd = rsqrtf(ss * (1.0f / Dm) - mean * mean + 1e-5f);
    float4 g0 = *(const float4*)(g + c0), g1 = *(const float4*)(g + c0 + 4);
    float4 b0 = *(const float4*)(b + c0), b1 = *(const float4*)(b + c0 + 4);
    union { uint4 u; ushort_t h[8]; } pk;
    pk.h[0] = f2bf((v0.x - mean) * rstd * g0.x + b0.x);
    pk.h[1] = f2bf((v0.y - mean) * rstd * g0.y + b0.y);
    pk.h[2] = f2bf((v0.z - mean) * rstd * g0.z + b0.z);
    pk.h[3] = f2bf((v0.w - mean) * rstd * g0.w + b0.w);
    pk.h[4] = f2bf((v1.x - mean) * rstd * g1.x + b1.x);
    pk.h[5] = f2bf((v1.y - mean) * rstd * g1.y + b1.y);
    pk.h[6] = f2bf((v1.z - mean) * rstd * g1.z + b1.z);
    pk.h[7] = f2bf((v1.w - mean) * rstd * g1.w + b1.w);
    *(uint4*)(xn + (size_t)tok * Dm + c0) = pk.u;
}

// ---------------- 8-wave MFMA GEMM: swizzled LDS + 3-deep counted-vmcnt pipeline ----------------
// Tiles t+1 and t+2 stay in flight across barriers; steady-state wait vmcnt(2*LPS).
// setprio(1) wraps the MFMA cluster (T5 - schedule has wave role-split).
// EPI 0: bf16 | 1: softplus(acc+bias) bf16 | 2: gelu(acc+bias) bf16
//     3: acc+bias+resid f32 | 4: acc+resid f32
template<int BM, int BN, int EPI>
__launch_bounds__(512)
__global__ void k_gemm8w(const ushort_t* __restrict__ A, const ushort_t* __restrict__ B,
                         void* __restrict__ C, int M, int K,
                         int lda, int ldb, int ldc, int nst,
                         const float* __restrict__ bias, const float* __restrict__ resid) {
    constexpr int FM = BM / 32;         // frags per wave in m
    constexpr int FN = BN / 64;         // frags per wave in n
    constexpr int AP = BM / 64;         // A staging passes
    constexpr int BP = BN / 64;         // B staging passes
    constexpr int LPS = AP + BP;        // global_load_lds instrs per thread per stage
    __shared__ __align__(16) ushort_t As[3][BM * 64];
    __shared__ __align__(16) ushort_t Bs[3][BN * 64];
    const int tid  = threadIdx.x;
    const int lane = tid & 63;
    const int w    = tid >> 6;          // 0..7
    const int wm   = w >> 2, wn = w & 3;
    const int lr   = lane & 15, lg = lane >> 4;
    const int m0   = blockIdx.x * BM, n0 = blockIdx.y * BN;

    f32x4 acc[FM][FN] = {};

    auto stage = [&](int buf, int kb) {
#pragma unroll
        for (int i = 0; i < AP; ++i) {
            const int chunk = i * 512 + tid;            // 16B chunks, physical [BM][8x16B]
            const int r    = chunk >> 3;
            const int ccol = chunk & 7;                 // physical 16B column
            const int csrc = ccol ^ (r & 7);            // logical column for this slot
            gll16(A + (size_t)(m0 + r) * lda + kb + csrc * 8, As[buf] + chunk * 8);
        }
#pragma unroll
        for (int i = 0; i < BP; ++i) {
            const int chunk = i * 512 + tid;
            const int r    = chunk >> 3;
            const int ccol = chunk & 7;
            const int csrc = ccol ^ (r & 7);
            gll16(B + (size_t)(n0 + r) * ldb + kb + csrc * 8, Bs[buf] + chunk * 8);
        }
    };

    auto compute = [&](int buf) {
        __builtin_amdgcn_s_setprio(1);
#pragma unroll
        for (int kk = 0; kk < 2; ++kk) {
            short8 a[FM], b[FN];
#pragma unroll
            for (int mf = 0; mf < FM; ++mf) {
                const int row = wm * (BM / 2) + mf * 16 + lr;
                const int pc  = (kk * 4 + lg) ^ (row & 7);
                a[mf] = *(const short8*)(As[buf] + (size_t)row * 64 + pc * 8);
            }
#pragma unroll
            for (int nf = 0; nf < FN; ++nf) {
                const int row = wn * (BN / 4) + nf * 16 + lr;
                const int pc  = (kk * 4 + lg) ^ (row & 7);
                b[nf] = *(const short8*)(Bs[buf] + (size_t)row * 64 + pc * 8);
            }
#pragma unroll
            for (int mf = 0; mf < FM; ++mf)
#pragma unroll
                for (int nf = 0; nf < FN; ++nf)
                    mfma_bf16(acc[mf][nf], a[mf], b[nf]);
        }
        __builtin_amdgcn_s_setprio(0);
    };

    const int nt = K >> 6;
    stage(0, 0);
    if (nt > 1) stage(1, 64);
    if (nt > 2) stage(2, 128);
    int cur = 0;
    for (int t = 0; t < nt; ++t) {
        if (t + 2 < nt)      vm_wait<2 * LPS>();   // tile t landed; t+1,t+2 in flight
        else if (t + 1 < nt) vm_wait<LPS>();
        else                 vm_wait<0>();
        __builtin_amdgcn_s_barrier();               // all waves' tile-t loads landed
        compute(cur);
        if (t + 3 < nt) {
            __builtin_amdgcn_s_barrier();           // all waves done reading buf[cur]
            stage(cur, (t + 3) << 6);               // prefetch tile t+3 (no drain)
        }
        cur = (cur == 2) ? 0 : cur + 1;
    }

#pragma unroll
    for (int mf = 0; mf < FM; ++mf)
#pragma unroll
        for (int nf = 0; nf < FN; ++nf) {
            const int gc = n0 + wn * (BN / 4) + nf * 16 + lr;
            if (gc >= nst) continue;
#pragma unroll
            for (int r = 0; r < 4; ++r) {
                const int gm = m0 + wm * (BM / 2) + mf * 16 + lg * 4 + r;
                if (gm >= M) continue;
                float v = acc[mf][nf][r];
                const size_t oi = (size_t)gm * ldc + gc;
                if constexpr (EPI == 0) {
                    ((ushort_t*)C)[oi] = f2bf(v);
                } else if constexpr (EPI == 1) {
                    v += bias[gc];
                    v = fmaxf(v, 0.0f) + __logf(1.0f + __expf(-fabsf(v)));
                    ((ushort_t*)C)[oi] = f2bf(v);
                } else if constexpr (EPI == 2) {
                    v += bias[gc];
                    v = 0.5f * v * (1.0f + fast_erf(v * 0.70710678118654752f));
                    ((ushort_t*)C)[oi] = f2bf(v);
                } else if constexpr (EPI == 3) {
                    v += bias[gc] + resid[oi];
                    ((float*)C)[oi] = v;
                } else if constexpr (EPI == 4) {
                    v += resid[oi];
                    ((float*)C)[oi] = v;
                }
            }
        }
}

// ---------------- depthwise causal conv (DC=4) + SiLU, transposed weights ----------------
__global__ void k_conv(const ushort_t* __restrict__ xz0, const float* __restrict__ cwT,
                       const float* __restrict__ cb, ushort_t* __restrict__ xi) {
    const int idx = blockIdx.x * 256 + threadIdx.x;   // MTOK*128 total
    if (idx >= MTOK * 128) return;
    const int g  = idx & 127;
    const int c0 = g * 8;
    const int l  = (idx >> 7) % Lq;
    const int s  = idx / (128 * Lq);
    const int p  = s / Bm, bi = s % Bm;
    float a[8];
    {
        float4 b0 = *(const float4*)(cb + c0);
        float4 b1 = *(const float4*)(cb + c0 + 4);
        a[0]=b0.x; a[1]=b0.y; a[2]=b0.z; a[3]=b0.w;
        a[4]=b1.x; a[5]=b1.y; a[6]=b1.z; a[7]=b1.w;
    }
#pragma unroll
    for (int d = 0; d < 4; ++d) {              // tap d: weight row d, token l-(3-d)
        const int lq = l - (3 - d);
        if (lq < 0) continue;
        const int tok = path_tok(p, bi, lq);
        union U { uint4 u; ushort_t h[8]; } xv;
        xv.u = *(const uint4*)(xz0 + (size_t)tok * (2 * DI) + c0);
        const float4 w0 = *(const float4*)(cwT + d * DI + c0);
        const float4 w1 = *(const float4*)(cwT + d * DI + c0 + 4);
        a[0] += bf2f(xv.h[0]) * w0.x;
        a[1] += bf2f(xv.h[1]) * w0.y;
        a[2] += bf2f(xv.h[2]) * w0.z;
        a[3] += bf2f(xv.h[3]) * w0.w;
        a[4] += bf2f(xv.h[4]) * w1.x;
        a[5] += bf2f(xv.h[5]) * w1.y;
        a[6] += bf2f(xv.h[6]) * w1.z;
        a[7] += bf2f(xv.h[7]) * w1.w;
    }
    union U { uint4 u; ushort_t h[8]; } ov;
#pragma unroll
    for (int k = 0; k < 8; ++k) {
        const float sv = a[k] / (1.0f + __expf(-a[k]));
        ov.h[k] = f2bf(sv);
    }
    *(uint4*)(xi + (size_t)(s * Lq + l) * DI + c0) = ov.u;
}

// ---------------- chunked selective scan (UNGATED y_loc/corr; pure sequential stride) ----------------
__global__ void k_scan1(const ushort_t* __restrict__ dt,
                        const ushort_t* __restrict__ xdbl, const float* __restrict__ A_log,
                        const float* __restrict__ Dp, ushort_t* __restrict__ xiy,
                        ushort_t* __restrict__ corr, float* __restrict__ Pb,
                        float* __restrict__ Sb) {
    const int blk = blockIdx.x;                    // (s*NCHK + j)*16 + cg
    const int cg = blk & 15;
    const int j  = (blk >> 4) & (NCHK - 1);
    const int s  = blk >> 8;
    const int ch = (cg << 6) + threadIdx.x;
    const int gl0 = j * CHK;
    const float Av = -__expf(A_log[ch]);
    const float Dv = Dp[ch];
    const size_t tok0 = (size_t)s * Lq + (size_t)gl0;
    const ushort_t* pdt = dt  + tok0 * DI + ch;
    ushort_t*       pxi = xiy + tok0 * DI + ch;
    ushort_t*       pco = corr + tok0 * DI + ch;
    const ushort_t* pbc = xdbl + tok0 * XD_LD;

    float h = 0.0f, pp = 1.0f;
    float dtv = bf2f(pdt[0]);
    float xiv = bf2f(pxi[0]);
    float bc  = bf2f(pbc[32]);
    float cc  = bf2f(pbc[33]);
    for (int l = 0; l < CHK; ++l) {
        float ndt = 0.f, nxi = 0.f, nbc = 0.f, ncc = 0.f;
        if (l + 1 < CHK) {
            const size_t o = (size_t)(l + 1);
            ndt = bf2f(pdt[o * DI]);
            nxi = bf2f(pxi[o * DI]);
            nbc = bf2f(pbc[o * XD_LD + 32]);
            ncc = bf2f(pbc[o * XD_LD + 33]);
        }
        const float dA = __expf(dtv * Av);
        h = dA * h + dtv * bc * xiv;
        pp *= dA;
        pxi[(size_t)l * DI] = f2bf(cc * h + Dv * xiv);
        pco[(size_t)l * DI] = f2bf(cc * pp);
        dtv = ndt; xiv = nxi; bc = nbc; cc = ncc;
    }
    const size_t pi = (size_t)(s * NCHK + j) * DI + ch;
    Pb[pi] = pp;
    Sb[pi] = h;
}

__global__ void k_scan2(const float* __restrict__ Pb, const float* __restrict__ Sb,
                        float* __restrict__ cb) {
    const int s  = blockIdx.x >> 4;
    const int ch = ((blockIdx.x & 15) << 6) + threadIdx.x;
    float c = 0.0f;
#pragma unroll
    for (int j = 0; j < NCHK; ++j) {
        const size_t pi = (size_t)(s * NCHK + j) * DI + ch;
        cb[pi] = c;
        c = Pb[pi] * c + Sb[pi];
    }
}

// ---------------- fused: 4-path gather of (y_loc + c*corr), summed, gated once ----------------
__global__ void k_ysum(const ushort_t* __restrict__ y, const ushort_t* __restrict__ corr,
                       const float* __restrict__ cbuf, const ushort_t* __restrict__ xz0,
                       ushort_t* __restrict__ ys) {
    const int tok = blockIdx.x;      // NTOK
    const int c0  = threadIdx.x * 8; // 128 threads * 8 = 1024 ch
    const int bi = tok / Lq;
    const int l1 = tok % Lq;
    const int t  = l1 / (Hh * Wd);
    const int hw = l1 % (Hh * Wd);
    const int hh = hw / Wd, ww = hw % Wd;
    const int l3 = (t * Wd + ww) * Hh + hh;
    const int q[4] = { l1, Lq - 1 - l1, l3, Lq - 1 - l3 };
    float a[8] = {};
#pragma unroll
    for (int p = 0; p < 4; ++p) {
        const int sq = p * Bm + bi;
        const size_t off = ((size_t)sq * Lq + q[p]) * DI + c0;
        union U { uint4 u; ushort_t h[8]; } yv, cv;
        yv.u = *(const uint4*)(y + off);
        cv.u = *(const uint4*)(corr + off);
        const int j = q[p] / CHK;
        const float* cp = cbuf + ((size_t)sq * NCHK + j) * DI + c0;
        float4 ca = *(const float4*)(cp);
        float4 cb2 = *(const float4*)(cp + 4);
        a[0] += bf2f(yv.h[0]) + ca.x  * bf2f(cv.h[0]);
        a[1] += bf2f(yv.h[1]) + ca.y  * bf2f(cv.h[1]);
        a[2] += bf2f(yv.h[2]) + ca.z  * bf2f(cv.h[2]);
        a[3] += bf2f(yv.h[3]) + ca.w  * bf2f(cv.h[3]);
        a[4] += bf2f(yv.h[4]) + cb2.x * bf2f(cv.h[4]);
        a[5] += bf2f(yv.h[5]) + cb2.y * bf2f(cv.h[5]);
        a[6] += bf2f(yv.h[6]) + cb2.z * bf2f(cv.h[6]);
        a[7] += bf2f(yv.h[7]) + cb2.w * bf2f(cv.h[7]);
    }
    // gate once: silu(z[tok]) is shared by all 4 path contributions
    union Z { uint4 u; ushort_t h[8]; } zv;
    zv.u = *(const uint4*)(xz0 + (size_t)tok * (2 * DI) + DI + c0);
    union U { uint4 u; ushort_t h[8]; } ov;
#pragma unroll
    for (int k = 0; k < 8; ++k) {
        const float z = bf2f(zv.h[k]);
        ov.h[k] = f2bf(a[k] * z / (1.0f + __expf(-z)));
    }
    *(uint4*)(ys + (size_t)tok * DI + c0) = ov.u;
}

// ---------------- LN2 ----------------
__global__ void k_ln2(const float* __restrict__ xin, const float* __restrict__ g,
                      const float* __restrict__ b, ushort_t* __restrict__ out) {
    const int tok  = blockIdx.x;
    const int lane = threadIdx.x;
    const int c0   = lane * 8;
    const float* row = xin + (size_t)tok * Dm;
    float4 v0 = *(const float4*)(row + c0);
    float4 v1 = *(const float4*)(row + c0 + 4);
    float s  = v0.x + v0.y + v0.z + v0.w + v1.x + v1.y + v1.z + v1.w;
    float ss = v0.x*v0.x + v0.y*v0.y + v0.z*v0.z + v0.w*v0.w
             + v1.x*v1.x + v1.y*v1.y + v1.z*v1.z + v1.w*v1.w;
#pragma unroll
    for (int o = 32; o >= 1; o >>= 1) { s += __shfl_xor(s, o); ss += __shfl_xor(ss, o); }
    const float mean = s * (1.0f / Dm);
    const float rstd = rsqrtf(ss * (1.0f / Dm) - mean * mean + 1e-5f);
    float4 g0 = *(const float4*)(g + c0), g1 = *(const float4*)(g + c0 + 4);
    float4 b0 = *(const float4*)(b + c0), b1 = *(const float4*)(b + c0 + 4);
    union { uint4 u; ushort_t h[8]; } pk;
    pk.h[0] = f2bf((v0.x - mean) * rstd * g0.x + b0.x);
    pk.h[1] = f2bf((v0.y - mean) * rstd * g0.y + b0.y);
    pk.h[2] = f2bf((v0.z - mean) * rstd * g0.z + b0.z);
    pk.h[3] = f2bf((v0.w - mean) * rstd * g0.w + b0.w);
    pk.h[4] = f2bf((v1.x - mean) * rstd * g1.x + b1.x);
    pk.h[5] = f2bf((v1.y - mean) * rstd * g1.y + b1.y);
    pk.h[6] = f2bf((v1.z - mean) * rstd * g1.z + b1.z);
    pk.h[7] = f2bf((v1.w - mean) * rstd * g1.w + b1.w);
    *(uint4*)(out + (size_t)tok * Dm + c0) = pk.u;
}

// ---------------- workspace layout ----------------
constexpr size_t OFF_CAT = 0;                                 // ln1 out, MPAD x Dm bf16
constexpr size_t SZ_CAT  = (size_t)MPAD * Dm * 2;
constexpr size_t OFF_XZ0 = OFF_CAT + SZ_CAT;                  // in-proj out, MPAD x 2DI bf16
constexpr size_t SZ_XZ0  = (size_t)MPAD * 2 * DI * 2;
constexpr size_t OFF_XI  = OFF_XZ0 + SZ_XZ0;                  // conv out / y_loc, MTOK x DI bf16
constexpr size_t SZ_XI   = (size_t)MTOK * DI * 2;
constexpr size_t OFF_XD  = OFF_XI + SZ_XI;                    // x_dbl, MTOK x 64 bf16
constexpr size_t SZ_XD   = (size_t)MTOK * XD_LD * 2;
constexpr size_t OFF_DT  = OFF_XD + SZ_XD;                    // dt, MTOK x DI bf16
constexpr size_t SZ_DT   = (size_t)MTOK * DI * 2;
constexpr size_t OFF_CO  = OFF_DT + SZ_DT;                    // corr, MTOK x DI bf16
constexpr size_t SZ_CO   = (size_t)MTOK * DI * 2;
constexpr size_t SZ_PSC  = (size_t)MBAT * NCHK * DI * 4;
constexpr size_t OFF_P   = OFF_CO + SZ_CO;
constexpr size_t OFF_S   = OFF_P + SZ_PSC;
constexpr size_t OFF_C   = OFF_S + SZ_PSC;
constexpr size_t OFF_YS  = OFF_C + SZ_PSC;                    // ysum, MPAD x DI bf16
constexpr size_t SZ_YS   = (size_t)MPAD * DI * 2;
constexpr size_t OFF_XR2 = OFF_YS + SZ_YS;                    // xr2, NTOK x Dm f32
constexpr size_t SZ_XR2  = (size_t)NTOK * Dm * 4;
constexpr size_t OFF_XL2 = OFF_XR2 + SZ_XR2;                  // ln2 out, MPAD x Dm bf16
constexpr size_t SZ_XL2  = (size_t)MPAD * Dm * 2;
constexpr size_t OFF_HM  = OFF_XL2 + SZ_XL2;                  // hmid, MPAD x 4Dm bf16
constexpr size_t SZ_HM   = (size_t)MPAD * 4 * Dm * 2;
constexpr size_t OFF_WIN = OFF_HM + SZ_HM;
constexpr size_t OFF_WOUT= OFF_WIN  + (size_t)2 * DI * Dm * 2;
constexpr size_t OFF_W1  = OFF_WOUT + (size_t)Dm * DI * 2;
constexpr size_t OFF_W2  = OFF_W1   + (size_t)4 * Dm * Dm * 2;
constexpr size_t OFF_WXP = OFF_W2   + (size_t)Dm * 4 * Dm * 2;   // 64 rows (padded)
constexpr size_t OFF_WDT = OFF_WXP  + (size_t)64 * DI * 2;       // w_dt, DI x 64 (padded)
constexpr size_t OFF_CWT = OFF_WDT  + (size_t)DI * 64 * 2;       // cwT, 4 x DI f32
constexpr size_t WS_NEED = OFF_CWT  + (size_t)4 * DI * 4;

extern "C" void kernel_launch(void* const* d_in, const int* in_sizes, int n_in,
                              void* d_out, int out_size, void* d_ws, size_t ws_size,
                              hipStream_t stream) {
    const float* x        = (const float*)d_in[0];
    const float* ln1_g    = (const float*)d_in[1];
    const float* ln1_b    = (const float*)d_in[2];
    const float* ln2_g    = (const float*)d_in[3];
    const float* ln2_b    = (const float*)d_in[4];
    const float* mlp_w1   = (const float*)d_in[5];
    const float* mlp_b1   = (const float*)d_in[6];
    const float* mlp_w2   = (const float*)d_in[7];
    const float* mlp_b2   = (const float*)d_in[8];
    const float* in_w     = (const float*)d_in[9];
    const float* conv_w   = (const float*)d_in[10];
    const float* conv_b   = (const float*)d_in[11];
    const float* xproj_w  = (const float*)d_in[12];
    const float* dtproj_w = (const float*)d_in[13];
    const float* dtproj_b = (const float*)d_in[14];
    const float* A_log    = (const float*)d_in[15];
    const float* D_param  = (const float*)d_in[16];
    const float* out_w    = (const float*)d_in[17];

    if (ws_size < WS_NEED) return;  // loud failure (d_out stays zero)

    char* ws = (char*)d_ws;
    ushort_t* cat   = (ushort_t*)(ws + OFF_CAT);
    ushort_t* xz0   = (ushort_t*)(ws + OFF_XZ0);
    ushort_t* xi    = (ushort_t*)(ws + OFF_XI);
    ushort_t* xdbl  = (ushort_t*)(ws + OFF_XD);
    ushort_t* dtb   = (ushort_t*)(ws + OFF_DT);
    ushort_t* corr  = (ushort_t*)(ws + OFF_CO);
    float*    Pb    = (float*)   (ws + OFF_P);
    float*    Sb    = (float*)   (ws + OFF_S);
    float*    cb    = (float*)   (ws + OFF_C);
    ushort_t* ysum  = (ushort_t*)(ws + OFF_YS);
    float*    xr2   = (float*)   (ws + OFF_XR2);
    ushort_t* xln2  = (ushort_t*)(ws + OFF_XL2);
    ushort_t* hmid  = (ushort_t*)(ws + OFF_HM);
    ushort_t* w_in  = (ushort_t*)(ws + OFF_WIN);
    ushort_t* w_out = (ushort_t*)(ws + OFF_WOUT);
    ushort_t* w_1   = (ushort_t*)(ws + OFF_W1);
    ushort_t* w_2   = (ushort_t*)(ws + OFF_W2);
    ushort_t* w_xp  = (ushort_t*)(ws + OFF_WXP);
    ushort_t* w_dt  = (ushort_t*)(ws + OFF_WDT);
    float*    cwT   = (float*)   (ws + OFF_CWT);

    auto cvt = [&](const float* s, ushort_t* d, int n) {
        k_f2bf<<<(n + 255) / 256, 256, 0, stream>>>(s, d, n);
    };
    cvt(in_w,     w_in,  2 * DI * Dm);
    cvt(out_w,    w_out, Dm * DI);
    cvt(mlp_w1,   w_1,   4 * Dm * Dm);
    cvt(mlp_w2,   w_2,   Dm * 4 * Dm);
    k_zero<<<(64 * DI + 255) / 256, 256, 0, stream>>>(w_xp, 64 * DI);
    cvt(xproj_w,  w_xp,  (DR + 2) * DI);
    k_zero<<<(DI * 64 + 255) / 256, 256, 0, stream>>>(w_dt, DI * 64);
    k_cvt_dt<<<(DI * DR + 255) / 256, 256, 0, stream>>>(dtproj_w, w_dt);
    k_cwT<<<(4 * DI + 255) / 256, 256, 0, stream>>>(conv_w, cwT);

    // LN1 (per-token, single copy)
    k_ln1<<<NTOK, 64, 0, stream>>>(x, ln1_g, ln1_b, cat);

    // xz0 = ln1(x) @ in_w^T   (5280 x 2048, K=512)
    k_gemm8w<64, 128, 0><<<dim3(MPAD / 64, (2 * DI) / 128), 512, 0, stream>>>(
        cat, w_in, xz0, NTOK, Dm, Dm, Dm, 2 * DI, 2 * DI, nullptr, nullptr);

    // depthwise causal conv + SiLU -> xi (path-ordered, gathered from xz0)
    k_conv<<<(MTOK * 128 + 255) / 256, 256, 0, stream>>>(xz0, cwT, conv_b, xi);

    // x_dbl = xi @ xproj^T  (writes all 64 cols; 34..63 land as exact zeros)
    k_gemm8w<64, 64, 0><<<dim3(MTOK / 64, 1), 512, 0, stream>>>(
        xi, w_xp, xdbl, MTOK, DI, DI, DI, XD_LD, 64, nullptr, nullptr);

    // dt = softplus(x_dbl @ w_dt_pad^T + b)  (K=64, cols 32..63 contribute 0)
    k_gemm8w<64, 128, 1><<<dim3(MTOK / 64, DI / 128), 512, 0, stream>>>(
        xdbl, w_dt, dtb, MTOK, 64, XD_LD, 64, DI, DI, dtproj_b, nullptr);

    // chunked selective scan (ungated; z factored out into ysum)
    k_scan1<<<MBAT * NCHK * 16, 64, 0, stream>>>(dtb, xdbl, A_log, D_param,
                                                 xi, corr, Pb, Sb);
    k_scan2<<<MBAT * 16, 64, 0, stream>>>(Pb, Sb, cb);

    // ysum = silu(z) * sum over 4 paths of gathered (y_loc + c*corr)
    k_ysum<<<NTOK, 128, 0, stream>>>(xi, corr, cb, xz0, ysum);

    // xr2 = x + ysum @ out_w^T
    k_gemm8w<64, 128, 4><<<dim3(MPAD / 64, Dm / 128), 512, 0, stream>>>(
        ysum, w_out, xr2, NTOK, DI, DI, DI, Dm, Dm, nullptr, x);

    // LN2
    k_ln2<<<NTOK, 64, 0, stream>>>(xr2, ln2_g, ln2_b, xln2);

    // hmid = gelu(xln2 @ w1^T + b1)  (fast erf)
    k_gemm8w<64, 128, 2><<<dim3(MPAD / 64, (4 * Dm) / 128), 512, 0, stream>>>(
        xln2, w_1, hmid, NTOK, Dm, Dm, Dm, 4 * Dm, 4 * Dm, mlp_b1, nullptr);

    // out = xr2 + hmid @ w2^T + b2  -> f32 d_out
    k_gemm8w<64, 128, 3><<<dim3(MPAD / 64, Dm / 128), 512, 0, stream>>>(
        hmid, w_2, (float*)d_out, NTOK, 4 * Dm, 4 * Dm, 4 * Dm, Dm, Dm, mlp_b2, xr2);
}

// Round 15
// 240.660 us; speedup vs baseline: 1.1100x; 1.1100x over previous
//
#include <hip/hip_runtime.h>
#include <math.h>

typedef __attribute__((ext_vector_type(8))) short short8;   // 8 x bf16 bits
typedef __attribute__((ext_vector_type(8))) __bf16 bf16x8;  // MFMA operand type
typedef __attribute__((ext_vector_type(4))) float f32x4;
typedef unsigned short ushort_t;

#define DEV __device__ __forceinline__

// ---------------- problem constants ----------------
constexpr int Dm   = 512;
constexpr int DI   = 1024;
constexpr int DR   = 32;
constexpr int Hh   = 16;
constexpr int Wd   = 11;
constexpr int Bm   = 10;          // b * (Sf/T) = 2*5
constexpr int Lq   = 528;         // T*H*W
constexpr int NTOK = Bm * Lq;     // 5280
constexpr int MBAT = 4 * Bm;      // 40 (4 scan paths)
constexpr int MTOK = MBAT * Lq;   // 21120
constexpr int XD_LD = 64;         // padded ld for x_dbl (34 cols used; 34..63 zero)
constexpr int NCHK = 16;          // scan chunks per sequence
constexpr int CHK  = Lq / NCHK;   // 33
constexpr int MPAD = 5376;        // NTOK padded to multiple of 128

// ---------------- bf16 helpers (explicit RNE) ----------------
DEV ushort_t f2bf(float f) {
    unsigned u = __float_as_uint(f);
    u += 0x7fffu + ((u >> 16) & 1u);
    return (ushort_t)(u >> 16);
}
DEV float bf2f(ushort_t h) { return __uint_as_float(((unsigned)h) << 16); }

DEV bf16x8 as_bf(short8 v) { return __builtin_bit_cast(bf16x8, v); }

DEV void mfma_bf16(f32x4& d, short8 a, short8 b) {
    d = __builtin_amdgcn_mfma_f32_16x16x32_bf16(as_bf(a), as_bf(b), d, 0, 0, 0);
}

// async global->LDS, 16B per lane (dest = wave-uniform base + lane*16)
DEV void gll16(const ushort_t* g, ushort_t* l) {
    __builtin_amdgcn_global_load_lds((const __attribute__((address_space(1))) void*)g,
                                     (__attribute__((address_space(3))) void*)l,
                                     16, 0, 0);
}

// counted vmcnt wait (literal immediates; memory clobber pins mem-op order)
template<int N> DEV void vm_wait() {
    if constexpr (N == 0) asm volatile("s_waitcnt vmcnt(0)" ::: "memory");
    else if constexpr (N == 2) asm volatile("s_waitcnt vmcnt(2)" ::: "memory");
    else if constexpr (N == 3) asm volatile("s_waitcnt vmcnt(3)" ::: "memory");
    else if constexpr (N == 4) asm volatile("s_waitcnt vmcnt(4)" ::: "memory");
    else asm volatile("s_waitcnt vmcnt(6)" ::: "memory");
}

// fast erf, Abramowitz-Stegun 7.1.26, |eps| <= 1.5e-7
DEV float fast_erf(float x) {
    const float ax = fabsf(x);
    const float t  = 1.0f / (1.0f + 0.3275911f * ax);
    const float y  = t * (0.254829592f + t * (-0.284496736f + t * (1.421413741f
                   + t * (-1.453152027f + t * 1.061405429f))));
    const float r  = 1.0f - y * __expf(-ax * ax);
    return copysignf(r, x);
}

// path-local index q (in path p's scan order) -> global token index (bi*Lq + l1)
DEV int path_tok(int p, int bi, int q) {
    int ql = (p & 1) ? (Lq - 1 - q) : q;   // paths 1,3 are flipped
    int l1;
    if (p < 2) {
        l1 = ql;
    } else {                               // path 2/3: q encodes (t*Wd+ww)*Hh+hh
        int t   = ql / (Hh * Wd);
        int rem = ql - t * (Hh * Wd);
        int ww  = rem / Hh;
        int hh  = rem - ww * Hh;
        l1 = (t * Hh + hh) * Wd + ww;
    }
    return bi * Lq + l1;
}

// ---------------- fused weight prep (7 launches -> 1) ----------------
// segments: [0] w_in cvt | [1] w_out cvt | [2] w_1 cvt | [3] w_2 cvt
//           [4] w_xp pad+cvt [64][DI] | [5] w_dt pad+cvt [DI][64] | [6] cwT transpose
constexpr int PR0 = 2 * DI * Dm;            // w_in
constexpr int PR1 = PR0 + Dm * DI;          // w_out
constexpr int PR2 = PR1 + 4 * Dm * Dm;      // w_1
constexpr int PR3 = PR2 + Dm * 4 * Dm;      // w_2
constexpr int PR4 = PR3 + 64 * DI;          // w_xp (padded)
constexpr int PR5 = PR4 + DI * 64;          // w_dt (padded)
constexpr int PR6 = PR5 + 4 * DI;           // cwT
__global__ void k_prep(const float* __restrict__ in_w,  const float* __restrict__ out_w,
                       const float* __restrict__ w1,    const float* __restrict__ w2,
                       const float* __restrict__ xproj, const float* __restrict__ dtproj,
                       const float* __restrict__ cw,
                       ushort_t* __restrict__ w_in,  ushort_t* __restrict__ w_out,
                       ushort_t* __restrict__ w_1,   ushort_t* __restrict__ w_2,
                       ushort_t* __restrict__ w_xp,  ushort_t* __restrict__ w_dt,
                       float* __restrict__ cwT) {
    int i = blockIdx.x * 256 + threadIdx.x;
    if (i < PR0)      { w_in [i]       = f2bf(in_w [i]); }
    else if (i < PR1) { w_out[i - PR0] = f2bf(out_w[i - PR0]); }
    else if (i < PR2) { w_1  [i - PR1] = f2bf(w1   [i - PR1]); }
    else if (i < PR3) { w_2  [i - PR2] = f2bf(w2   [i - PR2]); }
    else if (i < PR4) {
        int j = i - PR3;                    // [64][DI]: row n, col k
        int n = j / DI, k = j - n * DI;
        w_xp[j] = (n < DR + 2) ? f2bf(xproj[n * DI + k]) : (ushort_t)0;
    } else if (i < PR5) {
        int j = i - PR4;                    // [DI][64]: row r, col c
        int r = j >> 6, c = j & 63;
        w_dt[j] = (c < DR) ? f2bf(dtproj[r * DR + c]) : (ushort_t)0;
    } else if (i < PR6) {
        int j = i - PR5;                    // [4][DI]
        int d = j / DI, ch = j - d * DI;
        cwT[j] = cw[ch * 4 + d];
    }
}

// ---------------- LN1 (single row per token) ----------------
__global__ void k_ln1(const float* __restrict__ x, const float* __restrict__ g,
                      const float* __restrict__ b, ushort_t* __restrict__ xn) {
    const int tok  = blockIdx.x;     // 0..NTOK-1
    const int lane = threadIdx.x;    // 64 threads
    const int c0   = lane * 8;
    const float* row = x + (size_t)tok * Dm;
    float4 v0 = *(const float4*)(row + c0);
    float4 v1 = *(const float4*)(row + c0 + 4);
    float s  = v0.x + v0.y + v0.z + v0.w + v1.x + v1.y + v1.z + v1.w;
    float ss = v0.x*v0.x + v0.y*v0.y + v0.z*v0.z + v0.w*v0.w
             + v1.x*v1.x + v1.y*v1.y + v1.z*v1.z + v1.w*v1.w;
#pragma unroll
    for (int o = 32; o >= 1; o >>= 1) { s += __shfl_xor(s, o); ss += __shfl_xor(ss, o); }
    const float mean = s * (1.0f / Dm);
    const float rstd = rsqrtf(ss * (1.0f / Dm) - mean * mean + 1e-5f);
    float4 g0 = *(const float4*)(g + c0), g1 = *(const float4*)(g + c0 + 4);
    float4 b0 = *(const float4*)(b + c0), b1 = *(const float4*)(b + c0 + 4);
    union { uint4 u; ushort_t h[8]; } pk;
    pk.h[0] = f2bf((v0.x - mean) * rstd * g0.x + b0.x);
    pk.h[1] = f2bf((v0.y - mean) * rstd * g0.y + b0.y);
    pk.h[2] = f2bf((v0.z - mean) * rstd * g0.z + b0.z);
    pk.h[3] = f2bf((v0.w - mean) * rstd * g0.w + b0.w);
    pk.h[4] = f2bf((v1.x - mean) * rstd * g1.x + b1.x);
    pk.h[5] = f2bf((v1.y - mean) * rstd * g1.y + b1.y);
    pk.h[6] = f2bf((v1.z - mean) * rstd * g1.z + b1.z);
    pk.h[7] = f2bf((v1.w - mean) * rstd * g1.w + b1.w);
    *(uint4*)(xn + (size_t)tok * Dm + c0) = pk.u;
}

// ---------------- 8-wave dbuf MFMA GEMM: swizzled LDS + counted-vmcnt (R13 best) ----------------
// EPI 0: bf16 | 1: softplus(acc+bias) bf16 | 2: gelu(acc+bias) bf16
//     3: acc+bias+resid f32 | 4: acc+resid f32
template<int BM, int BN, int EPI>
__launch_bounds__(512)
__global__ void k_gemm8w(const ushort_t* __restrict__ A, const ushort_t* __restrict__ B,
                         void* __restrict__ C, int M, int K,
                         int lda, int ldb, int ldc, int nst,
                         const float* __restrict__ bias, const float* __restrict__ resid) {
    constexpr int FM = BM / 32;         // frags per wave in m
    constexpr int FN = BN / 64;         // frags per wave in n
    constexpr int AP = BM / 64;         // A staging passes
    constexpr int BP = BN / 64;         // B staging passes
    constexpr int LPS = AP + BP;        // global_load_lds instrs per thread per stage
    __shared__ __align__(16) ushort_t As[2][BM * 64];
    __shared__ __align__(16) ushort_t Bs[2][BN * 64];
    const int tid  = threadIdx.x;
    const int lane = tid & 63;
    const int w    = tid >> 6;          // 0..7
    const int wm   = w >> 2, wn = w & 3;
    const int lr   = lane & 15, lg = lane >> 4;
    const int m0   = blockIdx.x * BM, n0 = blockIdx.y * BN;

    f32x4 acc[FM][FN] = {};

    auto stage = [&](int buf, int kb) {
#pragma unroll
        for (int i = 0; i < AP; ++i) {
            const int chunk = i * 512 + tid;            // 16B chunks, physical [BM][8x16B]
            const int r    = chunk >> 3;
            const int ccol = chunk & 7;                 // physical 16B column
            const int csrc = ccol ^ (r & 7);            // logical column for this slot
            gll16(A + (size_t)(m0 + r) * lda + kb + csrc * 8, As[buf] + chunk * 8);
        }
#pragma unroll
        for (int i = 0; i < BP; ++i) {
            const int chunk = i * 512 + tid;
            const int r    = chunk >> 3;
            const int ccol = chunk & 7;
            const int csrc = ccol ^ (r & 7);
            gll16(B + (size_t)(n0 + r) * ldb + kb + csrc * 8, Bs[buf] + chunk * 8);
        }
    };

    auto compute = [&](int buf) {
#pragma unroll
        for (int kk = 0; kk < 2; ++kk) {
            short8 a[FM], b[FN];
#pragma unroll
            for (int mf = 0; mf < FM; ++mf) {
                const int row = wm * (BM / 2) + mf * 16 + lr;
                const int pc  = (kk * 4 + lg) ^ (row & 7);
                a[mf] = *(const short8*)(As[buf] + (size_t)row * 64 + pc * 8);
            }
#pragma unroll
            for (int nf = 0; nf < FN; ++nf) {
                const int row = wn * (BN / 4) + nf * 16 + lr;
                const int pc  = (kk * 4 + lg) ^ (row & 7);
                b[nf] = *(const short8*)(Bs[buf] + (size_t)row * 64 + pc * 8);
            }
#pragma unroll
            for (int mf = 0; mf < FM; ++mf)
#pragma unroll
                for (int nf = 0; nf < FN; ++nf)
                    mfma_bf16(acc[mf][nf], a[mf], b[nf]);
        }
    };

    const int nt = K >> 6;
    stage(0, 0);
    if (nt > 1) stage(1, 64);
    for (int t = 0; t < nt; ++t) {
        if (t + 1 < nt) vm_wait<LPS>();   // tile t landed; tile t+1 stays in flight
        else            vm_wait<0>();
        __builtin_amdgcn_s_barrier();      // all waves' tile-t loads landed
        compute(t & 1);
        if (t + 2 < nt) {
            __builtin_amdgcn_s_barrier();  // all waves done reading buf[t&1]
            stage(t & 1, (t + 2) << 6);    // prefetch tile t+2 (no drain)
        }
    }

#pragma unroll
    for (int mf = 0; mf < FM; ++mf)
#pragma unroll
        for (int nf = 0; nf < FN; ++nf) {
            const int gc = n0 + wn * (BN / 4) + nf * 16 + lr;
            if (gc >= nst) continue;
#pragma unroll
            for (int r = 0; r < 4; ++r) {
                const int gm = m0 + wm * (BM / 2) + mf * 16 + lg * 4 + r;
                if (gm >= M) continue;
                float v = acc[mf][nf][r];
                const size_t oi = (size_t)gm * ldc + gc;
                if constexpr (EPI == 0) {
                    ((ushort_t*)C)[oi] = f2bf(v);
                } else if constexpr (EPI == 1) {
                    v += bias[gc];
                    v = fmaxf(v, 0.0f) + __logf(1.0f + __expf(-fabsf(v)));
                    ((ushort_t*)C)[oi] = f2bf(v);
                } else if constexpr (EPI == 2) {
                    v += bias[gc];
                    v = 0.5f * v * (1.0f + fast_erf(v * 0.70710678118654752f));
                    ((ushort_t*)C)[oi] = f2bf(v);
                } else if constexpr (EPI == 3) {
                    v += bias[gc] + resid[oi];
                    ((float*)C)[oi] = v;
                } else if constexpr (EPI == 4) {
                    v += resid[oi];
                    ((float*)C)[oi] = v;
                }
            }
        }
}

// ---------------- depthwise causal conv (DC=4) + SiLU, transposed weights ----------------
__global__ void k_conv(const ushort_t* __restrict__ xz0, const float* __restrict__ cwT,
                       const float* __restrict__ cb, ushort_t* __restrict__ xi) {
    const int idx = blockIdx.x * 256 + threadIdx.x;   // MTOK*128 total
    if (idx >= MTOK * 128) return;
    const int g  = idx & 127;
    const int c0 = g * 8;
    const int l  = (idx >> 7) % Lq;
    const int s  = idx / (128 * Lq);
    const int p  = s / Bm, bi = s % Bm;
    float a[8];
    {
        float4 b0 = *(const float4*)(cb + c0);
        float4 b1 = *(const float4*)(cb + c0 + 4);
        a[0]=b0.x; a[1]=b0.y; a[2]=b0.z; a[3]=b0.w;
        a[4]=b1.x; a[5]=b1.y; a[6]=b1.z; a[7]=b1.w;
    }
#pragma unroll
    for (int d = 0; d < 4; ++d) {              // tap d: weight row d, token l-(3-d)
        const int lq = l - (3 - d);
        if (lq < 0) continue;
        const int tok = path_tok(p, bi, lq);
        union U { uint4 u; ushort_t h[8]; } xv;
        xv.u = *(const uint4*)(xz0 + (size_t)tok * (2 * DI) + c0);
        const float4 w0 = *(const float4*)(cwT + d * DI + c0);
        const float4 w1 = *(const float4*)(cwT + d * DI + c0 + 4);
        a[0] += bf2f(xv.h[0]) * w0.x;
        a[1] += bf2f(xv.h[1]) * w0.y;
        a[2] += bf2f(xv.h[2]) * w0.z;
        a[3] += bf2f(xv.h[3]) * w0.w;
        a[4] += bf2f(xv.h[4]) * w1.x;
        a[5] += bf2f(xv.h[5]) * w1.y;
        a[6] += bf2f(xv.h[6]) * w1.z;
        a[7] += bf2f(xv.h[7]) * w1.w;
    }
    union U { uint4 u; ushort_t h[8]; } ov;
#pragma unroll
    for (int k = 0; k < 8; ++k) {
        const float sv = a[k] / (1.0f + __expf(-a[k]));
        ov.h[k] = f2bf(sv);
    }
    *(uint4*)(xi + (size_t)(s * Lq + l) * DI + c0) = ov.u;
}

// ---------------- chunked selective scan (UNGATED y_loc/corr; pure sequential stride) ----------------
__global__ void k_scan1(const ushort_t* __restrict__ dt,
                        const ushort_t* __restrict__ xdbl, const float* __restrict__ A_log,
                        const float* __restrict__ Dp, ushort_t* __restrict__ xiy,
                        ushort_t* __restrict__ corr, float* __restrict__ Pb,
                        float* __restrict__ Sb) {
    const int blk = blockIdx.x;                    // (s*NCHK + j)*16 + cg
    const int cg = blk & 15;
    const int j  = (blk >> 4) & (NCHK - 1);
    const int s  = blk >> 8;
    const int ch = (cg << 6) + threadIdx.x;
    const int gl0 = j * CHK;
    const float Av = -__expf(A_log[ch]);
    const float Dv = Dp[ch];
    const size_t tok0 = (size_t)s * Lq + (size_t)gl0;
    const ushort_t* pdt = dt  + tok0 * DI + ch;
    ushort_t*       pxi = xiy + tok0 * DI + ch;
    ushort_t*       pco = corr + tok0 * DI + ch;
    const ushort_t* pbc = xdbl + tok0 * XD_LD;

    float h = 0.0f, pp = 1.0f;
    float dtv = bf2f(pdt[0]);
    float xiv = bf2f(pxi[0]);
    float bc  = bf2f(pbc[32]);
    float cc  = bf2f(pbc[33]);
    for (int l = 0; l < CHK; ++l) {
        float ndt = 0.f, nxi = 0.f, nbc = 0.f, ncc = 0.f;
        if (l + 1 < CHK) {
            const size_t o = (size_t)(l + 1);
            ndt = bf2f(pdt[o * DI]);
            nxi = bf2f(pxi[o * DI]);
            nbc = bf2f(pbc[o * XD_LD + 32]);
            ncc = bf2f(pbc[o * XD_LD + 33]);
        }
        const float dA = __expf(dtv * Av);
        h = dA * h + dtv * bc * xiv;
        pp *= dA;
        pxi[(size_t)l * DI] = f2bf(cc * h + Dv * xiv);
        pco[(size_t)l * DI] = f2bf(cc * pp);
        dtv = ndt; xiv = nxi; bc = nbc; cc = ncc;
    }
    const size_t pi = (size_t)(s * NCHK + j) * DI + ch;
    Pb[pi] = pp;
    Sb[pi] = h;
}

__global__ void k_scan2(const float* __restrict__ Pb, const float* __restrict__ Sb,
                        float* __restrict__ cb) {
    const int s  = blockIdx.x >> 4;
    const int ch = ((blockIdx.x & 15) << 6) + threadIdx.x;
    float c = 0.0f;
#pragma unroll
    for (int j = 0; j < NCHK; ++j) {
        const size_t pi = (size_t)(s * NCHK + j) * DI + ch;
        cb[pi] = c;
        c = Pb[pi] * c + Sb[pi];
    }
}

// ---------------- fused: 4-path gather of (y_loc + c*corr), summed, gated once ----------------
__global__ void k_ysum(const ushort_t* __restrict__ y, const ushort_t* __restrict__ corr,
                       const float* __restrict__ cbuf, const ushort_t* __restrict__ xz0,
                       ushort_t* __restrict__ ys) {
    const int tok = blockIdx.x;      // NTOK
    const int c0  = threadIdx.x * 8; // 128 threads * 8 = 1024 ch
    const int bi = tok / Lq;
    const int l1 = tok % Lq;
    const int t  = l1 / (Hh * Wd);
    const int hw = l1 % (Hh * Wd);
    const int hh = hw / Wd, ww = hw % Wd;
    const int l3 = (t * Wd + ww) * Hh + hh;
    const int q[4] = { l1, Lq - 1 - l1, l3, Lq - 1 - l3 };
    float a[8] = {};
#pragma unroll
    for (int p = 0; p < 4; ++p) {
        const int sq = p * Bm + bi;
        const size_t off = ((size_t)sq * Lq + q[p]) * DI + c0;
        union U { uint4 u; ushort_t h[8]; } yv, cv;
        yv.u = *(const uint4*)(y + off);
        cv.u = *(const uint4*)(corr + off);
        const int j = q[p] / CHK;
        const float* cp = cbuf + ((size_t)sq * NCHK + j) * DI + c0;
        float4 ca = *(const float4*)(cp);
        float4 cb2 = *(const float4*)(cp + 4);
        a[0] += bf2f(yv.h[0]) + ca.x  * bf2f(cv.h[0]);
        a[1] += bf2f(yv.h[1]) + ca.y  * bf2f(cv.h[1]);
        a[2] += bf2f(yv.h[2]) + ca.z  * bf2f(cv.h[2]);
        a[3] += bf2f(yv.h[3]) + ca.w  * bf2f(cv.h[3]);
        a[4] += bf2f(yv.h[4]) + cb2.x * bf2f(cv.h[4]);
        a[5] += bf2f(yv.h[5]) + cb2.y * bf2f(cv.h[5]);
        a[6] += bf2f(yv.h[6]) + cb2.z * bf2f(cv.h[6]);
        a[7] += bf2f(yv.h[7]) + cb2.w * bf2f(cv.h[7]);
    }
    // gate once: silu(z[tok]) is shared by all 4 path contributions
    union Z { uint4 u; ushort_t h[8]; } zv;
    zv.u = *(const uint4*)(xz0 + (size_t)tok * (2 * DI) + DI + c0);
    union U { uint4 u; ushort_t h[8]; } ov;
#pragma unroll
    for (int k = 0; k < 8; ++k) {
        const float z = bf2f(zv.h[k]);
        ov.h[k] = f2bf(a[k] * z / (1.0f + __expf(-z)));
    }
    *(uint4*)(ys + (size_t)tok * DI + c0) = ov.u;
}

// ---------------- LN2 ----------------
__global__ void k_ln2(const float* __restrict__ xin, const float* __restrict__ g,
                      const float* __restrict__ b, ushort_t* __restrict__ out) {
    const int tok  = blockIdx.x;
    const int lane = threadIdx.x;
    const int c0   = lane * 8;
    const float* row = xin + (size_t)tok * Dm;
    float4 v0 = *(const float4*)(row + c0);
    float4 v1 = *(const float4*)(row + c0 + 4);
    float s  = v0.x + v0.y + v0.z + v0.w + v1.x + v1.y + v1.z + v1.w;
    float ss = v0.x*v0.x + v0.y*v0.y + v0.z*v0.z + v0.w*v0.w
             + v1.x*v1.x + v1.y*v1.y + v1.z*v1.z + v1.w*v1.w;
#pragma unroll
    for (int o = 32; o >= 1; o >>= 1) { s += __shfl_xor(s, o); ss += __shfl_xor(ss, o); }
    const float mean = s * (1.0f / Dm);
    const float rstd = rsqrtf(ss * (1.0f / Dm) - mean * mean + 1e-5f);
    float4 g0 = *(const float4*)(g + c0), g1 = *(const float4*)(g + c0 + 4);
    float4 b0 = *(const float4*)(b + c0), b1 = *(const float4*)(b + c0 + 4);
    union { uint4 u; ushort_t h[8]; } pk;
    pk.h[0] = f2bf((v0.x - mean) * rstd * g0.x + b0.x);
    pk.h[1] = f2bf((v0.y - mean) * rstd * g0.y + b0.y);
    pk.h[2] = f2bf((v0.z - mean) * rstd * g0.z + b0.z);
    pk.h[3] = f2bf((v0.w - mean) * rstd * g0.w + b0.w);
    pk.h[4] = f2bf((v1.x - mean) * rstd * g1.x + b1.x);
    pk.h[5] = f2bf((v1.y - mean) * rstd * g1.y + b1.y);
    pk.h[6] = f2bf((v1.z - mean) * rstd * g1.z + b1.z);
    pk.h[7] = f2bf((v1.w - mean) * rstd * g1.w + b1.w);
    *(uint4*)(out + (size_t)tok * Dm + c0) = pk.u;
}

// ---------------- workspace layout ----------------
constexpr size_t OFF_CAT = 0;                                 // ln1 out, MPAD x Dm bf16
constexpr size_t SZ_CAT  = (size_t)MPAD * Dm * 2;
constexpr size_t OFF_XZ0 = OFF_CAT + SZ_CAT;                  // in-proj out, MPAD x 2DI bf16
constexpr size_t SZ_XZ0  = (size_t)MPAD * 2 * DI * 2;
constexpr size_t OFF_XI  = OFF_XZ0 + SZ_XZ0;                  // conv out / y_loc, MTOK x DI bf16
constexpr size_t SZ_XI   = (size_t)MTOK * DI * 2;
constexpr size_t OFF_XD  = OFF_XI + SZ_XI;                    // x_dbl, MTOK x 64 bf16
constexpr size_t SZ_XD   = (size_t)MTOK * XD_LD * 2;
constexpr size_t OFF_DT  = OFF_XD + SZ_XD;                    // dt, MTOK x DI bf16
constexpr size_t SZ_DT   = (size_t)MTOK * DI * 2;
constexpr size_t OFF_CO  = OFF_DT + SZ_DT;                    // corr, MTOK x DI bf16
constexpr size_t SZ_CO   = (size_t)MTOK * DI * 2;
constexpr size_t SZ_PSC  = (size_t)MBAT * NCHK * DI * 4;
constexpr size_t OFF_P   = OFF_CO + SZ_CO;
constexpr size_t OFF_S   = OFF_P + SZ_PSC;
constexpr size_t OFF_C   = OFF_S + SZ_PSC;
constexpr size_t OFF_YS  = OFF_C + SZ_PSC;                    // ysum, MPAD x DI bf16
constexpr size_t SZ_YS   = (size_t)MPAD * DI * 2;
constexpr size_t OFF_XR2 = OFF_YS + SZ_YS;                    // xr2, NTOK x Dm f32
constexpr size_t SZ_XR2  = (size_t)NTOK * Dm * 4;
constexpr size_t OFF_XL2 = OFF_XR2 + SZ_XR2;                  // ln2 out, MPAD x Dm bf16
constexpr size_t SZ_XL2  = (size_t)MPAD * Dm * 2;
constexpr size_t OFF_HM  = OFF_XL2 + SZ_XL2;                  // hmid, MPAD x 4Dm bf16
constexpr size_t SZ_HM   = (size_t)MPAD * 4 * Dm * 2;
constexpr size_t OFF_WIN = OFF_HM + SZ_HM;
constexpr size_t OFF_WOUT= OFF_WIN  + (size_t)2 * DI * Dm * 2;
constexpr size_t OFF_W1  = OFF_WOUT + (size_t)Dm * DI * 2;
constexpr size_t OFF_W2  = OFF_W1   + (size_t)4 * Dm * Dm * 2;
constexpr size_t OFF_WXP = OFF_W2   + (size_t)Dm * 4 * Dm * 2;   // 64 rows (padded)
constexpr size_t OFF_WDT = OFF_WXP  + (size_t)64 * DI * 2;       // w_dt, DI x 64 (padded)
constexpr size_t OFF_CWT = OFF_WDT  + (size_t)DI * 64 * 2;       // cwT, 4 x DI f32
constexpr size_t WS_NEED = OFF_CWT  + (size_t)4 * DI * 4;

extern "C" void kernel_launch(void* const* d_in, const int* in_sizes, int n_in,
                              void* d_out, int out_size, void* d_ws, size_t ws_size,
                              hipStream_t stream) {
    const float* x        = (const float*)d_in[0];
    const float* ln1_g    = (const float*)d_in[1];
    const float* ln1_b    = (const float*)d_in[2];
    const float* ln2_g    = (const float*)d_in[3];
    const float* ln2_b    = (const float*)d_in[4];
    const float* mlp_w1   = (const float*)d_in[5];
    const float* mlp_b1   = (const float*)d_in[6];
    const float* mlp_w2   = (const float*)d_in[7];
    const float* mlp_b2   = (const float*)d_in[8];
    const float* in_w     = (const float*)d_in[9];
    const float* conv_w   = (const float*)d_in[10];
    const float* conv_b   = (const float*)d_in[11];
    const float* xproj_w  = (const float*)d_in[12];
    const float* dtproj_w = (const float*)d_in[13];
    const float* dtproj_b = (const float*)d_in[14];
    const float* A_log    = (const float*)d_in[15];
    const float* D_param  = (const float*)d_in[16];
    const float* out_w    = (const float*)d_in[17];

    if (ws_size < WS_NEED) return;  // loud failure (d_out stays zero)

    char* ws = (char*)d_ws;
    ushort_t* cat   = (ushort_t*)(ws + OFF_CAT);
    ushort_t* xz0   = (ushort_t*)(ws + OFF_XZ0);
    ushort_t* xi    = (ushort_t*)(ws + OFF_XI);
    ushort_t* xdbl  = (ushort_t*)(ws + OFF_XD);
    ushort_t* dtb   = (ushort_t*)(ws + OFF_DT);
    ushort_t* corr  = (ushort_t*)(ws + OFF_CO);
    float*    Pb    = (float*)   (ws + OFF_P);
    float*    Sb    = (float*)   (ws + OFF_S);
    float*    cb    = (float*)   (ws + OFF_C);
    ushort_t* ysum  = (ushort_t*)(ws + OFF_YS);
    float*    xr2   = (float*)   (ws + OFF_XR2);
    ushort_t* xln2  = (ushort_t*)(ws + OFF_XL2);
    ushort_t* hmid  = (ushort_t*)(ws + OFF_HM);
    ushort_t* w_in  = (ushort_t*)(ws + OFF_WIN);
    ushort_t* w_out = (ushort_t*)(ws + OFF_WOUT);
    ushort_t* w_1   = (ushort_t*)(ws + OFF_W1);
    ushort_t* w_2   = (ushort_t*)(ws + OFF_W2);
    ushort_t* w_xp  = (ushort_t*)(ws + OFF_WXP);
    ushort_t* w_dt  = (ushort_t*)(ws + OFF_WDT);
    float*    cwT   = (float*)   (ws + OFF_CWT);

    // fused weight prep (single launch)
    k_prep<<<(PR6 + 255) / 256, 256, 0, stream>>>(
        in_w, out_w, mlp_w1, mlp_w2, xproj_w, dtproj_w, conv_w,
        w_in, w_out, w_1, w_2, w_xp, w_dt, cwT);

    // LN1 (per-token, single copy)
    k_ln1<<<NTOK, 64, 0, stream>>>(x, ln1_g, ln1_b, cat);

    // xz0 = ln1(x) @ in_w^T   (5280 x 2048, K=512)
    k_gemm8w<64, 128, 0><<<dim3(MPAD / 64, (2 * DI) / 128), 512, 0, stream>>>(
        cat, w_in, xz0, NTOK, Dm, Dm, Dm, 2 * DI, 2 * DI, nullptr, nullptr);

    // depthwise causal conv + SiLU -> xi (path-ordered, gathered from xz0)
    k_conv<<<(MTOK * 128 + 255) / 256, 256, 0, stream>>>(xz0, cwT, conv_b, xi);

    // x_dbl = xi @ xproj^T  (writes all 64 cols; 34..63 land as exact zeros)
    k_gemm8w<64, 64, 0><<<dim3(MTOK / 64, 1), 512, 0, stream>>>(
        xi, w_xp, xdbl, MTOK, DI, DI, DI, XD_LD, 64, nullptr, nullptr);

    // dt = softplus(x_dbl @ w_dt_pad^T + b)  (K=64, cols 32..63 contribute 0)
    k_gemm8w<64, 128, 1><<<dim3(MTOK / 64, DI / 128), 512, 0, stream>>>(
        xdbl, w_dt, dtb, MTOK, 64, XD_LD, 64, DI, DI, dtproj_b, nullptr);

    // chunked selective scan (ungated; z factored out into ysum)
    k_scan1<<<MBAT * NCHK * 16, 64, 0, stream>>>(dtb, xdbl, A_log, D_param,
                                                 xi, corr, Pb, Sb);
    k_scan2<<<MBAT * 16, 64, 0, stream>>>(Pb, Sb, cb);

    // ysum = silu(z) * sum over 4 paths of gathered (y_loc + c*corr)
    k_ysum<<<NTOK, 128, 0, stream>>>(xi, corr, cb, xz0, ysum);

    // xr2 = x + ysum @ out_w^T
    k_gemm8w<64, 128, 4><<<dim3(MPAD / 64, Dm / 128), 512, 0, stream>>>(
        ysum, w_out, xr2, NTOK, DI, DI, DI, Dm, Dm, nullptr, x);

    // LN2
    k_ln2<<<NTOK, 64, 0, stream>>>(xr2, ln2_g, ln2_b, xln2);

    // hmid = gelu(xln2 @ w1^T + b1)  (fast erf)
    k_gemm8w<64, 128, 2><<<dim3(MPAD / 64, (4 * Dm) / 128), 512, 0, stream>>>(
        xln2, w_1, hmid, NTOK, Dm, Dm, Dm, 4 * Dm, 4 * Dm, mlp_b1, nullptr);

    // out = xr2 + hmid @ w2^T + b2  -> f32 d_out
    k_gemm8w<64, 128, 3><<<dim3(MPAD / 64, Dm / 128), 512, 0, stream>>>(
        hmid, w_2, (float*)d_out, NTOK, 4 * Dm, 4 * Dm, 4 * Dm, Dm, Dm, mlp_b2, xr2);
}